// Round 2
// 473.915 us; speedup vs baseline: 1.0729x; 1.0729x over previous
//
#include <hip/hip_runtime.h>
#include <hip/hip_fp16.h>

#define N_NODES 1000000
#define NUM_EDGES 262144
#define CARD 50000
#define EMB 128
#define EDGE_DIM 27

// Native vector types (HIP's float4/uint4 are structs; the nontemporal
// builtins require true vector-of-scalar types).
typedef float vfloat4 __attribute__((ext_vector_type(4)));
typedef unsigned int vuint4 __attribute__((ext_vector_type(4)));

// ---------------------------------------------------------------------------
// Workspace layout (bytes):
//   [0, 128)            : folded msg-path weights ws[0..27]
//   [4096, 4096+16MB)   : packed x records, uint4 per node
//   [16004096, +115.2MB): emb_feats converted to fp16
// ---------------------------------------------------------------------------
#define XPACK_OFF 4096
#define EMB16_OFF (XPACK_OFF + (size_t)N_NODES * 16)              // 16,004,096
#define EMB_ELEMS (9ull * CARD * EMB)                             // 57,600,000
#define WS_NEEDED (EMB16_OFF + EMB_ELEMS * 2)                     // ~131.2 MB

// ---------------------------------------------------------------------------
// Prep kernel: fold msg-path weights.
//   ws[0..26] = w2[j] = sum_k out_w[k] * edge_w[k,j]
//   ws[27]    = b2    = sum_k edge_b[k] * out_w[k] + out_b
// ---------------------------------------------------------------------------
__global__ void prep_kernel(const float* __restrict__ edge_w,
                            const float* __restrict__ edge_b,
                            const float* __restrict__ out_w,
                            const float* __restrict__ out_b,
                            float* __restrict__ ws) {
    int j = threadIdx.x;
    if (j < EDGE_DIM) {
        float s = 0.f;
        for (int k = 0; k < EMB; ++k) s += out_w[k] * edge_w[k * EDGE_DIM + j];
        ws[j] = s;
    } else if (j == EDGE_DIM) {
        float s = out_b[0];
        for (int k = 0; k < EMB; ++k) s += edge_b[k] * out_w[k];
        ws[EDGE_DIM] = s;
    }
}

// ---------------------------------------------------------------------------
// Pack x: per node, resolve the type-dependent column select ONCE and store
// 4 combined row indices (h*CARD+i, 19 bits) + type (bits 20:21 of w0) +
// pad flag (bit 22 of w0) as one uint4. 40 B -> 16 B per node; the 16 MB
// table is trivially L3-resident, and the main kernel's second dependent
// load becomes one dwordx4 with zero select VALU.
// x is read NT: nothing else reads it, keep it out of L3.
// ---------------------------------------------------------------------------
__global__ __launch_bounds__(256) void pack_x_kernel(const int* __restrict__ x,
                                                     uint4* __restrict__ xp) {
    int i = blockIdx.x * 256 + threadIdx.x;
    if (i >= N_NODES) return;
    const int* r = x + (size_t)i * 10;
    const int t  = __builtin_nontemporal_load(r + 0);
    const int c1 = __builtin_nontemporal_load(r + 1);
    const int c2 = __builtin_nontemporal_load(r + 2);
    const int c3 = __builtin_nontemporal_load(r + 3);
    const int c4 = __builtin_nontemporal_load(r + 4);
    const int c5 = __builtin_nontemporal_load(r + 5);
    const int c6 = __builtin_nontemporal_load(r + 6);
    const int c7 = __builtin_nontemporal_load(r + 7);
    const int c8 = __builtin_nontemporal_load(r + 8);
    const int c9 = __builtin_nontemporal_load(r + 9);
    unsigned i0, i1, i2, i3, pad = 0;
    if (t == 0) {
        i0 = (unsigned)c1;
        i1 = 1u * CARD + (unsigned)c2;
        i2 = 2u * CARD + (unsigned)c3;
        i3 = 3u * CARD + (unsigned)c4;
    } else if (t == 1) {
        i0 = i1 = i2 = i3 = 4u * CARD + (unsigned)c5;
        pad = 1u;
    } else {
        i0 = 5u * CARD + (unsigned)c6;
        i1 = 6u * CARD + (unsigned)c7;
        i2 = 7u * CARD + (unsigned)c8;
        i3 = 8u * CARD + (unsigned)c9;
    }
    uint4 o;
    o.x = i0 | ((unsigned)t << 20) | (pad << 22);
    o.y = i1;
    o.z = i2;
    o.w = i3;
    xp[i] = o;
}

// ---------------------------------------------------------------------------
// Convert emb_feats fp32 -> fp16 (115.2 MB). Working set of the gather
// kernel drops to ~131 MB << 256 MB L3, so the 5.2x intra-dispatch row
// reuse becomes L3 hits instead of HBM re-misses. fp32 source is read NT
// (we never want the fp32 copy cached; the fp16 copy is what must stay).
// 8 elems/thread, exact grid: 57.6M / (8*256) = 28125 blocks.
// ---------------------------------------------------------------------------
__global__ __launch_bounds__(256) void cvt_emb_kernel(const float* __restrict__ src,
                                                      __half* __restrict__ dst) {
    size_t i = ((size_t)blockIdx.x * 256 + threadIdx.x) * 8;
    vfloat4 a = __builtin_nontemporal_load((const vfloat4*)(src + i));
    vfloat4 b = __builtin_nontemporal_load((const vfloat4*)(src + i + 4));
    __half2 h0 = __floats2half2_rn(a.x, a.y);
    __half2 h1 = __floats2half2_rn(a.z, a.w);
    __half2 h2 = __floats2half2_rn(b.x, b.y);
    __half2 h3 = __floats2half2_rn(b.z, b.w);
    vuint4 o;
    o.x = *(unsigned*)&h0;
    o.y = *(unsigned*)&h1;
    o.z = *(unsigned*)&h2;
    o.w = *(unsigned*)&h3;
    *(vuint4*)(dst + i) = o;
}

// ---------------------------------------------------------------------------
// Main kernel (fp16 table path): TWO edges per wave (6 node encodes),
// 4 waves/block. Structure identical to the verified fp32 kernel:
//  - wave-uniform edge id -> scalar index path (s_load of packed x record);
//  - all 24 fp16 row-gathers (dword/lane, 256 B/row) + 6 type rows + msg +
//    out_w issued, then sched_barrier(0) pins them before any consumer;
//  - msg non-temporal (pure streaming);
//  - t==1 padding gathers alias one real row (L1 hit), weight 0.
// ---------------------------------------------------------------------------
__global__ __launch_bounds__(256, 4) void edge_pred_fp16(
    const uint4* __restrict__ xp, const int* __restrict__ src,
    const int* __restrict__ dst, const int* __restrict__ neg_dst,
    const float* __restrict__ msg, const float* __restrict__ emb_type,
    const __half* __restrict__ e16, const float* __restrict__ out_w,
    const float* __restrict__ ws, float* __restrict__ out) {
    const int lane = threadIdx.x & 63;
    const int wave = threadIdx.x >> 6;
    const int e0 = __builtin_amdgcn_readfirstlane(blockIdx.x * 8 + wave * 2);

    const int half = lane >> 5;  // 0 -> edge0, 1 -> edge1
    const int hl = lane & 31;
    const int loff = lane * 2;

    // ---- scalar index loads (s_load) ----
    int nodes[6];
    nodes[0] = src[e0];     nodes[1] = dst[e0];     nodes[2] = neg_dst[e0];
    nodes[3] = src[e0 + 1]; nodes[4] = dst[e0 + 1]; nodes[5] = neg_dst[e0 + 1];

    // ---- msg term (non-temporal, independent, issued early) ----
    float mterm = 0.f;
    if (hl < EDGE_DIM) {
        mterm = __builtin_nontemporal_load(msg + (size_t)(e0 + half) * EDGE_DIM + hl) * ws[hl];
    }

    // ---- issue ALL gathers before any accumulation ----
    float2 v0[6];
    unsigned u[6][4];
    float wpad[6];
#pragma unroll
    for (int n = 0; n < 6; ++n) {
        const uint4 px = xp[nodes[n]];
        const unsigned t = (px.x >> 20) & 3u;
        wpad[n] = (px.x & (1u << 22)) ? 0.f : 1.f;
        const size_t i0 = (size_t)(px.x & 0xFFFFFu);

        v0[n] = *(const float2*)(emb_type + (size_t)t * EMB + loff);
        u[n][0] = *(const unsigned*)((const char*)e16 + (i0 * EMB + loff) * 2);
        u[n][1] = *(const unsigned*)((const char*)e16 + ((size_t)px.y * EMB + loff) * 2);
        u[n][2] = *(const unsigned*)((const char*)e16 + ((size_t)px.z * EMB + loff) * 2);
        u[n][3] = *(const unsigned*)((const char*)e16 + ((size_t)px.w * EMB + loff) * 2);
    }
    const float2 wv = *(const float2*)(out_w + loff);

    // Nothing may cross: all loads stay issued & live here.
    __builtin_amdgcn_sched_barrier(0);

    // ---- accumulate ----
    float hx[6], hy[6];
#pragma unroll
    for (int n = 0; n < 6; ++n) {
        const float2 f1 = __half22float2(*(const __half2*)&u[n][0]);
        const float2 f2 = __half22float2(*(const __half2*)&u[n][1]);
        const float2 f3 = __half22float2(*(const __half2*)&u[n][2]);
        const float2 f4 = __half22float2(*(const __half2*)&u[n][3]);
        const float ax = v0[n].x + f1.x;   // type row + col0 (always w=1)
        const float ay = v0[n].y + f1.y;
        const float bx = f2.x + f3.x + f4.x;
        const float by = f2.y + f3.y + f4.y;
        hx[n] = ax + wpad[n] * bx;
        hy[n] = ay + wpad[n] * by;
    }

    // edge0: src=0, dst=1, neg=2 ; edge1: src=3, dst=4, neg=5
    float p0 = fmaxf(hx[0] + hx[1], 0.f) * wv.x + fmaxf(hy[0] + hy[1], 0.f) * wv.y;
    float q0 = fmaxf(hx[0] + hx[2], 0.f) * wv.x + fmaxf(hy[0] + hy[2], 0.f) * wv.y;
    float p1 = fmaxf(hx[3] + hx[4], 0.f) * wv.x + fmaxf(hy[3] + hy[4], 0.f) * wv.y;
    float q1 = fmaxf(hx[3] + hx[5], 0.f) * wv.x + fmaxf(hy[3] + hy[5], 0.f) * wv.y;

    if (half == 0) { p0 += mterm; q0 += mterm; }
    else           { p1 += mterm; q1 += mterm; }

    // ---- reduction: xor-32, pack per-half, 5 shared steps ----
    p0 += __shfl_xor(p0, 32, 64);
    q0 += __shfl_xor(q0, 32, 64);
    p1 += __shfl_xor(p1, 32, 64);
    q1 += __shfl_xor(q1, 32, 64);
    float pz = half ? p1 : p0;
    float qz = half ? q1 : q0;
#pragma unroll
    for (int off = 16; off > 0; off >>= 1) {
        pz += __shfl_xor(pz, off, 64);
        qz += __shfl_xor(qz, off, 64);
    }

    if (hl == 0) {
        const float b2 = ws[EDGE_DIM];
        const int e = e0 + half;
        out[e] = pz + b2;
        out[NUM_EDGES + e] = qz + b2;
    }
}

// ---------------------------------------------------------------------------
// Fallback main kernel (fp32 path, verified at 508 us): used only if the
// workspace is too small for the fp16 table.
// ---------------------------------------------------------------------------
__global__ __launch_bounds__(256, 4) void edge_pred_kernel(
    const int* __restrict__ x, const int* __restrict__ src,
    const int* __restrict__ dst, const int* __restrict__ neg_dst,
    const float* __restrict__ msg, const float* __restrict__ emb_type,
    const float* __restrict__ emb_feats, const float* __restrict__ out_w,
    const float* __restrict__ ws, float* __restrict__ out) {
    const int lane = threadIdx.x & 63;
    const int wave = threadIdx.x >> 6;
    const int e0 = __builtin_amdgcn_readfirstlane(blockIdx.x * 8 + wave * 2);

    const int half = lane >> 5;
    const int hl = lane & 31;
    const int loff = lane * 2;

    int nodes[6];
    nodes[0] = src[e0];     nodes[1] = dst[e0];     nodes[2] = neg_dst[e0];
    nodes[3] = src[e0 + 1]; nodes[4] = dst[e0 + 1]; nodes[5] = neg_dst[e0 + 1];

    float mterm = 0.f;
    if (hl < EDGE_DIM) {
        mterm = __builtin_nontemporal_load(msg + (size_t)(e0 + half) * EDGE_DIM + hl) * ws[hl];
    }

    float2 v[6][5];
    float wpad[6];
#pragma unroll
    for (int n = 0; n < 6; ++n) {
        const int* xr = x + (size_t)nodes[n] * 10;
        const int t = xr[0];
        const int c1 = xr[1], c2 = xr[2], c3 = xr[3], c4 = xr[4], c5 = xr[5],
                  c6 = xr[6], c7 = xr[7], c8 = xr[8], c9 = xr[9];
        const int i0 = (t == 0) ? c1 : (t == 1) ? c5 : c6;
        const int i1 = (t == 0) ? c2 : (t == 1) ? c5 : c7;
        const int i2 = (t == 0) ? c3 : (t == 1) ? c5 : c8;
        const int i3 = (t == 0) ? c4 : (t == 1) ? c5 : c9;
        const int h0 = (t == 0) ? 0 : (t == 1) ? 4 : 5;
        const int h1 = (t == 0) ? 1 : (t == 1) ? 4 : 6;
        const int h2 = (t == 0) ? 2 : (t == 1) ? 4 : 7;
        const int h3 = (t == 0) ? 3 : (t == 1) ? 4 : 8;
        wpad[n] = (t == 1) ? 0.f : 1.f;

        v[n][0] = *(const float2*)(emb_type + (size_t)t * EMB + loff);
        v[n][1] = *(const float2*)(emb_feats + ((size_t)h0 * CARD + (size_t)i0) * EMB + loff);
        v[n][2] = *(const float2*)(emb_feats + ((size_t)h1 * CARD + (size_t)i1) * EMB + loff);
        v[n][3] = *(const float2*)(emb_feats + ((size_t)h2 * CARD + (size_t)i2) * EMB + loff);
        v[n][4] = *(const float2*)(emb_feats + ((size_t)h3 * CARD + (size_t)i3) * EMB + loff);
    }
    const float2 wv = *(const float2*)(out_w + loff);

    __builtin_amdgcn_sched_barrier(0);

    float hx[6], hy[6];
#pragma unroll
    for (int n = 0; n < 6; ++n) {
        const float ax = v[n][0].x + v[n][1].x;
        const float ay = v[n][0].y + v[n][1].y;
        const float bx = v[n][2].x + v[n][3].x + v[n][4].x;
        const float by = v[n][2].y + v[n][3].y + v[n][4].y;
        hx[n] = ax + wpad[n] * bx;
        hy[n] = ay + wpad[n] * by;
    }

    float p0 = fmaxf(hx[0] + hx[1], 0.f) * wv.x + fmaxf(hy[0] + hy[1], 0.f) * wv.y;
    float q0 = fmaxf(hx[0] + hx[2], 0.f) * wv.x + fmaxf(hy[0] + hy[2], 0.f) * wv.y;
    float p1 = fmaxf(hx[3] + hx[4], 0.f) * wv.x + fmaxf(hy[3] + hy[4], 0.f) * wv.y;
    float q1 = fmaxf(hx[3] + hx[5], 0.f) * wv.x + fmaxf(hy[3] + hy[5], 0.f) * wv.y;

    if (half == 0) { p0 += mterm; q0 += mterm; }
    else           { p1 += mterm; q1 += mterm; }

    p0 += __shfl_xor(p0, 32, 64);
    q0 += __shfl_xor(q0, 32, 64);
    p1 += __shfl_xor(p1, 32, 64);
    q1 += __shfl_xor(q1, 32, 64);
    float pz = half ? p1 : p0;
    float qz = half ? q1 : q0;
#pragma unroll
    for (int off = 16; off > 0; off >>= 1) {
        pz += __shfl_xor(pz, off, 64);
        qz += __shfl_xor(qz, off, 64);
    }

    if (hl == 0) {
        const float b2 = ws[EDGE_DIM];
        const int e = e0 + half;
        out[e] = pz + b2;
        out[NUM_EDGES + e] = qz + b2;
    }
}

extern "C" void kernel_launch(void* const* d_in, const int* in_sizes, int n_in,
                              void* d_out, int out_size, void* d_ws, size_t ws_size,
                              hipStream_t stream) {
    const int* x = (const int*)d_in[0];
    const int* src = (const int*)d_in[1];
    const int* dst = (const int*)d_in[2];
    const int* neg_dst = (const int*)d_in[3];
    const float* msg = (const float*)d_in[4];
    const float* emb_type = (const float*)d_in[5];
    const float* emb_feats = (const float*)d_in[6];
    const float* edge_w = (const float*)d_in[7];
    const float* edge_b = (const float*)d_in[8];
    const float* out_w = (const float*)d_in[9];
    const float* out_b = (const float*)d_in[10];
    float* out = (float*)d_out;
    float* ws = (float*)d_ws;

    prep_kernel<<<1, 64, 0, stream>>>(edge_w, edge_b, out_w, out_b, ws);

    const int blocks = NUM_EDGES / 8;  // 4 waves/block, 2 edges/wave

    if (ws_size >= WS_NEEDED) {
        uint4* xp = (uint4*)((char*)d_ws + XPACK_OFF);
        __half* e16 = (__half*)((char*)d_ws + EMB16_OFF);
        pack_x_kernel<<<(N_NODES + 255) / 256, 256, 0, stream>>>(x, xp);
        cvt_emb_kernel<<<28125, 256, 0, stream>>>(emb_feats, e16);
        edge_pred_fp16<<<blocks, 256, 0, stream>>>(xp, src, dst, neg_dst, msg,
                                                   emb_type, e16, out_w, ws, out);
    } else {
        edge_pred_kernel<<<blocks, 256, 0, stream>>>(x, src, dst, neg_dst, msg,
                                                     emb_type, emb_feats, out_w,
                                                     ws, out);
    }
}